// Round 6
// baseline (504.651 us; speedup 1.0000x reference)
//
#include <hip/hip_runtime.h>
#include <hip/hip_bf16.h>

// Sizes fixed by the problem
#define B  2048
#define D  4096
#define D3 12288   // 3*D
#define L  3

struct Ptrs8 { const float* p[8]; };

typedef float          f32x4 __attribute__((ext_vector_type(4)));
typedef unsigned int   u32x2 __attribute__((ext_vector_type(2)));
typedef unsigned int   u32x4 __attribute__((ext_vector_type(4)));

__device__ __forceinline__ f32x4 ldnt4(const float* p) {
    return __builtin_nontemporal_load(reinterpret_cast<const f32x4*>(p));
}
__device__ __forceinline__ f32x4 ld4(const float* p) {
    return *reinterpret_cast<const f32x4*>(p);
}
__device__ __forceinline__ float bf_lo(unsigned int u) {
    union { unsigned int u; float f; } v; v.u = u << 16; return v.f;
}
__device__ __forceinline__ float bf_hi(unsigned int u) {
    union { unsigned int u; float f; } v; v.u = u & 0xFFFF0000u; return v.f;
}
// pack f32x4 -> 4 bf16 (rne) and store 8B
__device__ __forceinline__ void st_bf16x4(unsigned short* dst, f32x4 w) {
    __hip_bfloat162 p0 = __float22bfloat162_rn(make_float2(w.x, w.y));
    __hip_bfloat162 p1 = __float22bfloat162_rn(make_float2(w.z, w.w));
    unsigned int u0, u1;
    __builtin_memcpy(&u0, &p0, 4);
    __builtin_memcpy(&u1, &p1, 4);
    u32x2 v; v.x = u0; v.y = u1;
    *reinterpret_cast<u32x2*>(dst) = v;
}

// ---------------------------------------------------------------------------
// K1: column means of the 8 [B, D] inputs (NT: streamed once).
// ---------------------------------------------------------------------------
__global__ void k_mean_partial(Ptrs8 in, float* __restrict__ partials) {
    const int cc = blockIdx.x, rc = blockIdx.y, m = blockIdx.z;
    const float* __restrict__ src = in.p[m];
    const int col0 = cc * 1024 + threadIdx.x * 4;
    const size_t base = (size_t)(rc * 32) * D + col0;
    f32x4 a0 = {0,0,0,0}, a1 = {0,0,0,0}, a2 = {0,0,0,0}, a3 = {0,0,0,0};
    #pragma unroll
    for (int r = 0; r < 32; r += 4) {
        a0 += ldnt4(src + base + (size_t)(r + 0) * D);
        a1 += ldnt4(src + base + (size_t)(r + 1) * D);
        a2 += ldnt4(src + base + (size_t)(r + 2) * D);
        a3 += ldnt4(src + base + (size_t)(r + 3) * D);
    }
    const f32x4 acc = (a0 + a1) + (a2 + a3);
    *reinterpret_cast<f32x4*>(partials + ((size_t)(m * 64 + rc)) * D + col0) = acc;
}

__global__ void k_mean_finalize(const float* __restrict__ partials,
                                float* __restrict__ means,
                                float* __restrict__ h,
                                float* __restrict__ svec) {
    const int d = blockIdx.x * 256 + threadIdx.x;
    float mv[8];
    #pragma unroll
    for (int m = 0; m < 8; ++m) {
        float s = 0.f;
        for (int rc = 0; rc < 64; ++rc) s += partials[(size_t)(m * 64 + rc) * D + d];
        mv[m] = s * (1.0f / (float)B);
        means[m * D + d] = mv[m];
    }
    float ssum = 0.f;
    #pragma unroll
    for (int j = 0; j < 4; ++j) {          // shared rows = pre means (inputs 4..7)
        h[j * D + d] = mv[4 + j];
        ssum += mv[4 + j];
    }
    #pragma unroll
    for (int s = 0; s < 4; ++s)            // stream rows = now means (inputs 0..3)
        h[(4 + s) * D + d] = mv[s];
    svec[d] = ssum;
}

// ---------------------------------------------------------------------------
// K3: aggmsg[d'] = sum_d svec[d] * W[d][d']  (NT on W: streamed once/layer).
// ---------------------------------------------------------------------------
__global__ void k_aggmsg_partial(const float* __restrict__ Wl,
                                 const float* __restrict__ svec,
                                 float* __restrict__ partials) {
    const int col0 = blockIdx.x * 1024 + threadIdx.x * 4;
    const int row0 = blockIdx.y * 16;
    f32x4 a0 = {0,0,0,0}, a1 = {0,0,0,0}, a2 = {0,0,0,0}, a3 = {0,0,0,0};
    #pragma unroll
    for (int r = 0; r < 16; r += 4) {
        a0 += svec[row0 + r + 0] * ldnt4(Wl + (size_t)(row0 + r + 0) * D + col0);
        a1 += svec[row0 + r + 1] * ldnt4(Wl + (size_t)(row0 + r + 1) * D + col0);
        a2 += svec[row0 + r + 2] * ldnt4(Wl + (size_t)(row0 + r + 2) * D + col0);
        a3 += svec[row0 + r + 3] * ldnt4(Wl + (size_t)(row0 + r + 3) * D + col0);
    }
    const f32x4 acc = (a0 + a1) + (a2 + a3);
    *reinterpret_cast<f32x4*>(partials + (size_t)blockIdx.y * D + col0) = acc;
}

__global__ void k_aggmsg_reduce(const float* __restrict__ partials,
                                float* __restrict__ aggmsg) {
    const int d = blockIdx.x * 256 + threadIdx.x;
    float s = 0.f;
    for (int r = 0; r < 256; ++r) s += partials[(size_t)r * D + d];
    aggmsg[d] = s;
}

// ---------------------------------------------------------------------------
// K4 (layer 0): fused gates, j-split structure.
// Blocks [0,1536): gh. Block owns weight rows kbase..kbase+7; ALL 4 waves
//   load the same 8 rows (L2 serves redundancy); wave w handles h-vectors
//   j = {2w, 2w+1} only -> per wave-iter: 8KB weights, 2 h-loads, 64 FMA.
//   Wave w converts/stores bf16 for rows {2w, 2w+1}.
// Blocks [1536,1920): gi0. Wave owns 8 distinct rows; streams aggmsg.
// No LDS, no barriers, no NT on weights (LLC serves ~half across replays).
// ---------------------------------------------------------------------------
__global__ __launch_bounds__(256)
void k_gates_f32(const float* __restrict__ w_ih,
                 const float* __restrict__ w_hh,
                 const float* __restrict__ h,
                 const float* __restrict__ aggmsg,
                 const float* __restrict__ b_ih,
                 const float* __restrict__ b_hh,
                 float* __restrict__ gi0,
                 float* __restrict__ gh,
                 unsigned short* __restrict__ wih_bf,
                 unsigned short* __restrict__ whh_bf) {
    const int wid = threadIdx.x >> 6, lane = threadIdx.x & 63;
    if (blockIdx.x < 1536) {
        const int kbase = blockIdx.x * 8;
        const int j0 = wid * 2;
        float acc[8][2] = {};
        for (int i = 0; i < 16; ++i) {
            const int idx = i * 256 + lane * 4;
            // hot loads first (in-order vmcnt: keep them ahead of cold loads)
            const f32x4 hv0 = ld4(h + j0 * D + idx);
            const f32x4 hv1 = ld4(h + (j0 + 1) * D + idx);
            f32x4 w[8];
            #pragma unroll
            for (int r = 0; r < 8; ++r)
                w[r] = ld4(w_hh + (size_t)(kbase + r) * D + idx);
            // this wave's bf16 store duty: rows 2*wid, 2*wid+1
            st_bf16x4(whh_bf + (size_t)(kbase + j0) * D + idx, w[j0]);
            st_bf16x4(whh_bf + (size_t)(kbase + j0 + 1) * D + idx, w[j0 + 1]);
            #pragma unroll
            for (int r = 0; r < 8; ++r) {
                acc[r][0] += w[r].x * hv0.x + w[r].y * hv0.y
                           + w[r].z * hv0.z + w[r].w * hv0.w;
                acc[r][1] += w[r].x * hv1.x + w[r].y * hv1.y
                           + w[r].z * hv1.z + w[r].w * hv1.w;
            }
        }
        #pragma unroll
        for (int r = 0; r < 8; ++r)
            #pragma unroll
            for (int jj = 0; jj < 2; ++jj) {
                float v = acc[r][jj];
                #pragma unroll
                for (int off = 32; off; off >>= 1) v += __shfl_xor(v, off);
                if (lane == 0)
                    gh[(size_t)(j0 + jj) * D3 + kbase + r] = v + b_hh[kbase + r];
            }
    } else {
        const int k0 = (blockIdx.x - 1536) * 32 + wid * 8;
        float acc[8] = {};
        for (int i = 0; i < 16; ++i) {
            const int idx = i * 256 + lane * 4;
            const f32x4 av = ld4(aggmsg + idx);
            f32x4 w[8];
            #pragma unroll
            for (int r = 0; r < 8; ++r)
                w[r] = ld4(w_ih + (size_t)(k0 + r) * D + idx);
            #pragma unroll
            for (int r = 0; r < 8; ++r)
                st_bf16x4(wih_bf + (size_t)(k0 + r) * D + idx, w[r]);
            #pragma unroll
            for (int r = 0; r < 8; ++r)
                acc[r] += w[r].x * av.x + w[r].y * av.y
                        + w[r].z * av.z + w[r].w * av.w;
        }
        #pragma unroll
        for (int r = 0; r < 8; ++r) {
            float v = acc[r];
            #pragma unroll
            for (int off = 32; off; off >>= 1) v += __shfl_xor(v, off);
            if (lane == 0) gi0[k0 + r] = v + b_ih[k0 + r];
        }
    }
}

// ---------------------------------------------------------------------------
// K4b (layers 1-2): same j-split structure from the bf16 copies
// (LLC-resident). 16B = 8 bf16 per row per iter; 8 iters.
// ---------------------------------------------------------------------------
__global__ __launch_bounds__(256)
void k_gates_bf(const unsigned short* __restrict__ wih_bf,
                const unsigned short* __restrict__ whh_bf,
                const float* __restrict__ h,
                const float* __restrict__ aggmsg,
                const float* __restrict__ b_ih,
                const float* __restrict__ b_hh,
                float* __restrict__ gi0,
                float* __restrict__ gh) {
    const int wid = threadIdx.x >> 6, lane = threadIdx.x & 63;
    if (blockIdx.x < 1536) {
        const int kbase = blockIdx.x * 8;
        const int j0 = wid * 2;
        float acc[8][2] = {};
        for (int i = 0; i < 8; ++i) {
            const int idx = i * 512 + lane * 8;
            const f32x4 h0a = ld4(h + j0 * D + idx);
            const f32x4 h0b = ld4(h + j0 * D + idx + 4);
            const f32x4 h1a = ld4(h + (j0 + 1) * D + idx);
            const f32x4 h1b = ld4(h + (j0 + 1) * D + idx + 4);
            u32x4 w[8];
            #pragma unroll
            for (int r = 0; r < 8; ++r)
                w[r] = *reinterpret_cast<const u32x4*>(
                    whh_bf + (size_t)(kbase + r) * D + idx);
            #pragma unroll
            for (int r = 0; r < 8; ++r) {
                const float f0 = bf_lo(w[r].x), f1 = bf_hi(w[r].x);
                const float f2 = bf_lo(w[r].y), f3 = bf_hi(w[r].y);
                const float f4 = bf_lo(w[r].z), f5 = bf_hi(w[r].z);
                const float f6 = bf_lo(w[r].w), f7 = bf_hi(w[r].w);
                acc[r][0] += f0 * h0a.x + f1 * h0a.y + f2 * h0a.z + f3 * h0a.w
                           + f4 * h0b.x + f5 * h0b.y + f6 * h0b.z + f7 * h0b.w;
                acc[r][1] += f0 * h1a.x + f1 * h1a.y + f2 * h1a.z + f3 * h1a.w
                           + f4 * h1b.x + f5 * h1b.y + f6 * h1b.z + f7 * h1b.w;
            }
        }
        #pragma unroll
        for (int r = 0; r < 8; ++r)
            #pragma unroll
            for (int jj = 0; jj < 2; ++jj) {
                float v = acc[r][jj];
                #pragma unroll
                for (int off = 32; off; off >>= 1) v += __shfl_xor(v, off);
                if (lane == 0)
                    gh[(size_t)(j0 + jj) * D3 + kbase + r] = v + b_hh[kbase + r];
            }
    } else {
        const int k0 = (blockIdx.x - 1536) * 32 + wid * 8;
        float acc[8] = {};
        for (int i = 0; i < 8; ++i) {
            const int idx = i * 512 + lane * 8;
            const f32x4 a0 = ld4(aggmsg + idx);
            const f32x4 a1 = ld4(aggmsg + idx + 4);
            u32x4 w[8];
            #pragma unroll
            for (int r = 0; r < 8; ++r)
                w[r] = *reinterpret_cast<const u32x4*>(
                    wih_bf + (size_t)(k0 + r) * D + idx);
            #pragma unroll
            for (int r = 0; r < 8; ++r)
                acc[r] += bf_lo(w[r].x) * a0.x + bf_hi(w[r].x) * a0.y
                        + bf_lo(w[r].y) * a0.z + bf_hi(w[r].y) * a0.w
                        + bf_lo(w[r].z) * a1.x + bf_hi(w[r].z) * a1.y
                        + bf_lo(w[r].w) * a1.z + bf_hi(w[r].w) * a1.w;
        }
        #pragma unroll
        for (int r = 0; r < 8; ++r) {
            float v = acc[r];
            #pragma unroll
            for (int off = 32; off; off >>= 1) v += __shfl_xor(v, off);
            if (lane == 0) gi0[k0 + r] = v + b_ih[k0 + r];
        }
    }
}

// ---------------------------------------------------------------------------
// K6: GRU pointwise update; rows 0-3 (shared) use gi = b_ih (agg = 0).
// ---------------------------------------------------------------------------
__device__ __forceinline__ float sigmoidf_(float x) {
    return 1.0f / (1.0f + __expf(-x));
}

__global__ void k_gru(const float* __restrict__ gi0,
                      const float* __restrict__ gh,
                      const float* __restrict__ b_ih,
                      float* __restrict__ h,
                      float* __restrict__ svec) {
    const int d = blockIdx.x * 256 + threadIdx.x;
    const float bir = b_ih[d], biz = b_ih[D + d], bin = b_ih[2 * D + d];
    const float gir = gi0[d],  giz = gi0[D + d],  gin = gi0[2 * D + d];
    float ssum = 0.f;
    #pragma unroll
    for (int j = 0; j < 8; ++j) {
        const float ir = (j < 4) ? bir : gir;
        const float iz = (j < 4) ? biz : giz;
        const float in = (j < 4) ? bin : gin;
        const float hr = gh[(size_t)j * D3 + d];
        const float hz = gh[(size_t)j * D3 + D + d];
        const float hn = gh[(size_t)j * D3 + 2 * D + d];
        const float hv = h[j * D + d];
        const float r = sigmoidf_(ir + hr);
        const float z = sigmoidf_(iz + hz);
        const float n = tanhf(in + r * hn);
        const float hnew = (1.f - z) * n + z * hv;
        h[j * D + d] = hnew;
        if (j < 4) ssum += hnew;
    }
    svec[d] = ssum;
}

// ---------------------------------------------------------------------------
// K7: loss = 10 * sum_s mean_d (h0_s - pre_mean_s)^2.
// ---------------------------------------------------------------------------
__global__ void k_loss(const float* __restrict__ h,
                       const float* __restrict__ means,
                       float* __restrict__ out) {
    __shared__ float red[4];
    float acc = 0.f;
    for (int idx = threadIdx.x; idx < 4 * D; idx += 256) {
        const int s = idx >> 12;
        const int d = idx & (D - 1);
        const float diff = h[(4 + s) * D + d] - means[(4 + s) * D + d];
        acc += diff * diff;
    }
    #pragma unroll
    for (int off = 32; off; off >>= 1) acc += __shfl_xor(acc, off);
    const int wave = threadIdx.x >> 6, lane = threadIdx.x & 63;
    if (lane == 0) red[wave] = acc;
    __syncthreads();
    if (threadIdx.x == 0)
        out[0] = (red[0] + red[1] + red[2] + red[3]) * (10.0f / (float)D);
}

// ---------------------------------------------------------------------------
extern "C" void kernel_launch(void* const* d_in, const int* in_sizes, int n_in,
                              void* d_out, int out_size, void* d_ws, size_t ws_size,
                              hipStream_t stream) {
    const float* W    = (const float*)d_in[8];
    const float* w_ih = (const float*)d_in[9];
    const float* w_hh = (const float*)d_in[10];
    const float* b_ih = (const float*)d_in[11];
    const float* b_hh = (const float*)d_in[12];

    float* ws     = (float*)d_ws;
    float* mpart  = ws;                    // 8*64*D
    float* means  = mpart  + 8 * 64 * D;   // 8*D
    float* h      = means  + 8 * D;        // 8*D
    float* svec   = h      + 8 * D;        // D
    float* apart  = svec   + D;            // 256*D
    float* aggmsg = apart  + 256 * D;      // D
    float* gi0    = aggmsg + D;            // D3
    float* gh     = gi0    + D3;           // 8*D3
    float* wbase  = gh     + 8 * D3;
    unsigned short* wih_bf = (unsigned short*)wbase;   // D3*D bf16 = 96 MB
    unsigned short* whh_bf = wih_bf + (size_t)D3 * D;  // D3*D bf16 = 96 MB

    Ptrs8 in8;
    for (int i = 0; i < 8; ++i) in8.p[i] = (const float*)d_in[i];

    k_mean_partial<<<dim3(4, 64, 8), 256, 0, stream>>>(in8, mpart);
    k_mean_finalize<<<16, 256, 0, stream>>>(mpart, means, h, svec);

    for (int l = 0; l < L; ++l) {
        const float* Wl = W + (size_t)l * D * D;
        k_aggmsg_partial<<<dim3(4, 256), 256, 0, stream>>>(Wl, svec, apart);
        k_aggmsg_reduce<<<16, 256, 0, stream>>>(apart, aggmsg);
        if (l == 0)
            k_gates_f32<<<1920, 256, 0, stream>>>(w_ih, w_hh, h, aggmsg,
                                                  b_ih, b_hh, gi0, gh,
                                                  wih_bf, whh_bf);
        else
            k_gates_bf<<<1920, 256, 0, stream>>>(wih_bf, whh_bf, h, aggmsg,
                                                 b_ih, b_hh, gi0, gh);
        k_gru<<<16, 256, 0, stream>>>(gi0, gh, b_ih, h, svec);
    }

    k_loss<<<1, 256, 0, stream>>>(h, means, (float*)d_out);
}

// Round 7
// 421.208 us; speedup vs baseline: 1.1981x; 1.1981x over previous
//
#include <hip/hip_runtime.h>
#include <hip/hip_bf16.h>

// Sizes fixed by the problem
#define B  2048
#define D  4096
#define D3 12288   // 3*D
#define L  3

struct Ptrs8 { const float* p[8]; };

typedef float          f32x4 __attribute__((ext_vector_type(4)));
typedef unsigned int   u32x2 __attribute__((ext_vector_type(2)));

__device__ __forceinline__ f32x4 ldnt4(const float* p) {
    return __builtin_nontemporal_load(reinterpret_cast<const f32x4*>(p));
}
__device__ __forceinline__ f32x4 ld4(const float* p) {
    return *reinterpret_cast<const f32x4*>(p);
}
__device__ __forceinline__ float dot4(f32x4 a, f32x4 b) {
    return a.x * b.x + a.y * b.y + a.z * b.z + a.w * b.w;
}
__device__ __forceinline__ float bf_lo(unsigned int u) {
    union { unsigned int u; float f; } v; v.u = u << 16; return v.f;
}
__device__ __forceinline__ float bf_hi(unsigned int u) {
    union { unsigned int u; float f; } v; v.u = u & 0xFFFF0000u; return v.f;
}
// pack f32x4 -> 4 bf16 (rne) and store 8B
__device__ __forceinline__ void st_bf16x4(unsigned short* dst, f32x4 w) {
    __hip_bfloat162 p0 = __float22bfloat162_rn(make_float2(w.x, w.y));
    __hip_bfloat162 p1 = __float22bfloat162_rn(make_float2(w.z, w.w));
    unsigned int u0, u1;
    __builtin_memcpy(&u0, &p0, 4);
    __builtin_memcpy(&u1, &p1, 4);
    u32x2 v; v.x = u0; v.y = u1;
    *reinterpret_cast<u32x2*>(dst) = v;
}

// ---------------------------------------------------------------------------
// K1: column means of the 8 [B, D] inputs (NT: streamed once). ~roofline.
// ---------------------------------------------------------------------------
__global__ void k_mean_partial(Ptrs8 in, float* __restrict__ partials) {
    const int cc = blockIdx.x, rc = blockIdx.y, m = blockIdx.z;
    const float* __restrict__ src = in.p[m];
    const int col0 = cc * 1024 + threadIdx.x * 4;
    const size_t base = (size_t)(rc * 32) * D + col0;
    f32x4 a0 = {0,0,0,0}, a1 = {0,0,0,0}, a2 = {0,0,0,0}, a3 = {0,0,0,0};
    #pragma unroll
    for (int r = 0; r < 32; r += 4) {
        a0 += ldnt4(src + base + (size_t)(r + 0) * D);
        a1 += ldnt4(src + base + (size_t)(r + 1) * D);
        a2 += ldnt4(src + base + (size_t)(r + 2) * D);
        a3 += ldnt4(src + base + (size_t)(r + 3) * D);
    }
    const f32x4 acc = (a0 + a1) + (a2 + a3);
    *reinterpret_cast<f32x4*>(partials + ((size_t)(m * 64 + rc)) * D + col0) = acc;
}

__global__ void k_mean_finalize(const float* __restrict__ partials,
                                float* __restrict__ means,
                                float* __restrict__ h,
                                float* __restrict__ svec) {
    const int d = blockIdx.x * 256 + threadIdx.x;
    float mv[8];
    #pragma unroll
    for (int m = 0; m < 8; ++m) {
        float s = 0.f;
        for (int rc = 0; rc < 64; ++rc) s += partials[(size_t)(m * 64 + rc) * D + d];
        mv[m] = s * (1.0f / (float)B);
        means[m * D + d] = mv[m];
    }
    float ssum = 0.f;
    #pragma unroll
    for (int j = 0; j < 4; ++j) {          // shared rows = pre means (inputs 4..7)
        h[j * D + d] = mv[4 + j];
        ssum += mv[4 + j];
    }
    #pragma unroll
    for (int s = 0; s < 4; ++s)            // stream rows = now means (inputs 0..3)
        h[(4 + s) * D + d] = mv[s];
    svec[d] = ssum;
}

// ---------------------------------------------------------------------------
// K3: aggmsg[d'] = sum_d svec[d] * W[d][d']  (NT on W: streamed once/layer).
// ---------------------------------------------------------------------------
__global__ void k_aggmsg_partial(const float* __restrict__ Wl,
                                 const float* __restrict__ svec,
                                 float* __restrict__ partials) {
    const int col0 = blockIdx.x * 1024 + threadIdx.x * 4;
    const int row0 = blockIdx.y * 16;
    f32x4 a0 = {0,0,0,0}, a1 = {0,0,0,0}, a2 = {0,0,0,0}, a3 = {0,0,0,0};
    #pragma unroll
    for (int r = 0; r < 16; r += 4) {
        a0 += svec[row0 + r + 0] * ldnt4(Wl + (size_t)(row0 + r + 0) * D + col0);
        a1 += svec[row0 + r + 1] * ldnt4(Wl + (size_t)(row0 + r + 1) * D + col0);
        a2 += svec[row0 + r + 2] * ldnt4(Wl + (size_t)(row0 + r + 2) * D + col0);
        a3 += svec[row0 + r + 3] * ldnt4(Wl + (size_t)(row0 + r + 3) * D + col0);
    }
    const f32x4 acc = (a0 + a1) + (a2 + a3);
    *reinterpret_cast<f32x4*>(partials + (size_t)blockIdx.y * D + col0) = acc;
}

__global__ void k_aggmsg_reduce(const float* __restrict__ partials,
                                float* __restrict__ aggmsg) {
    const int d = blockIdx.x * 256 + threadIdx.x;
    float s = 0.f;
    for (int r = 0; r < 256; ++r) s += partials[(size_t)r * D + d];
    aggmsg[d] = s;
}

// ---------------------------------------------------------------------------
// K4 (layer 0): fused gates, 1-iter software pipeline with hot-before-cold
// vmcnt queue ordering. Per tile: issue 8 hot h-loads FIRST (in-order vmcnt:
// they wait only on themselves), then issue NEXT tile's cold weight loads
// (full iteration of slack), consume current weights from registers.
// Blocks [0,1536): gh, 2 w_hh rows/wave. Blocks [1536,2304): gi0, 4 rows/wave.
// Emits bf16 weight copies for layers 1-2.
// ---------------------------------------------------------------------------
__global__ __launch_bounds__(256)
void k_gates_f32(const float* __restrict__ w_ih,
                 const float* __restrict__ w_hh,
                 const float* __restrict__ h,
                 const float* __restrict__ aggmsg,
                 const float* __restrict__ b_ih,
                 const float* __restrict__ b_hh,
                 float* __restrict__ gi0,
                 float* __restrict__ gh,
                 unsigned short* __restrict__ wih_bf,
                 unsigned short* __restrict__ whh_bf) {
    const int wid = threadIdx.x >> 6, lane = threadIdx.x & 63;
    const int col = lane * 4;
    if (blockIdx.x < 1536) {
        const int k0 = (blockIdx.x * 4 + wid) * 2;       // 2 rows/wave
        const float* __restrict__ wr0 = w_hh + (size_t)k0 * D;
        const float* __restrict__ wr1 = wr0 + D;
        float acc0[8] = {}, acc1[8] = {};
        f32x4 wa0 = ld4(wr0 + col);
        f32x4 wa1 = ld4(wr1 + col);
        for (int i = 0; i < 16; ++i) {
            const int idx  = i * 256 + col;
            const int nidx = ((i + 1) & 15) * 256 + col;  // wrap: iter15 dummy
            f32x4 hv[8];
            #pragma unroll
            for (int j = 0; j < 8; ++j) hv[j] = ld4(h + j * D + idx);
            const f32x4 wb0 = ld4(wr0 + nidx);            // cold, 1 iter slack
            const f32x4 wb1 = ld4(wr1 + nidx);
            #pragma unroll
            for (int j = 0; j < 8; ++j) {
                acc0[j] += dot4(wa0, hv[j]);
                acc1[j] += dot4(wa1, hv[j]);
            }
            st_bf16x4(whh_bf + (size_t)(k0 + 0) * D + idx, wa0);
            st_bf16x4(whh_bf + (size_t)(k0 + 1) * D + idx, wa1);
            wa0 = wb0; wa1 = wb1;
        }
        #pragma unroll
        for (int j = 0; j < 8; ++j) {
            float v0 = acc0[j], v1 = acc1[j];
            #pragma unroll
            for (int off = 32; off; off >>= 1) {
                v0 += __shfl_xor(v0, off);
                v1 += __shfl_xor(v1, off);
            }
            if (lane == 0) {
                gh[(size_t)j * D3 + k0 + 0] = v0 + b_hh[k0 + 0];
                gh[(size_t)j * D3 + k0 + 1] = v1 + b_hh[k0 + 1];
            }
        }
    } else {
        const int k0 = ((blockIdx.x - 1536) * 4 + wid) * 4;  // 4 rows/wave
        const float* __restrict__ wr = w_ih + (size_t)k0 * D;
        float acc[4] = {};
        f32x4 wa0 = ld4(wr + 0 * D + col);
        f32x4 wa1 = ld4(wr + 1 * D + col);
        f32x4 wa2 = ld4(wr + 2 * D + col);
        f32x4 wa3 = ld4(wr + 3 * D + col);
        for (int i = 0; i < 16; ++i) {
            const int idx  = i * 256 + col;
            const int nidx = ((i + 1) & 15) * 256 + col;
            const f32x4 av = ld4(aggmsg + idx);           // hot first
            const f32x4 wb0 = ld4(wr + 0 * D + nidx);
            const f32x4 wb1 = ld4(wr + 1 * D + nidx);
            const f32x4 wb2 = ld4(wr + 2 * D + nidx);
            const f32x4 wb3 = ld4(wr + 3 * D + nidx);
            acc[0] += dot4(wa0, av);
            acc[1] += dot4(wa1, av);
            acc[2] += dot4(wa2, av);
            acc[3] += dot4(wa3, av);
            st_bf16x4(wih_bf + (size_t)(k0 + 0) * D + idx, wa0);
            st_bf16x4(wih_bf + (size_t)(k0 + 1) * D + idx, wa1);
            st_bf16x4(wih_bf + (size_t)(k0 + 2) * D + idx, wa2);
            st_bf16x4(wih_bf + (size_t)(k0 + 3) * D + idx, wa3);
            wa0 = wb0; wa1 = wb1; wa2 = wb2; wa3 = wb3;
        }
        #pragma unroll
        for (int r = 0; r < 4; ++r) {
            float v = acc[r];
            #pragma unroll
            for (int off = 32; off; off >>= 1) v += __shfl_xor(v, off);
            if (lane == 0) gi0[k0 + r] = v + b_ih[k0 + r];
        }
    }
}

// ---------------------------------------------------------------------------
// K4b (layers 1-2): same pipeline from bf16 copies (LLC-resident).
// hh: 2 rows/wave, 16 tiles x 256 cols, u32x2 weight loads.
// ---------------------------------------------------------------------------
__global__ __launch_bounds__(256)
void k_gates_bf(const unsigned short* __restrict__ wih_bf,
                const unsigned short* __restrict__ whh_bf,
                const float* __restrict__ h,
                const float* __restrict__ aggmsg,
                const float* __restrict__ b_ih,
                const float* __restrict__ b_hh,
                float* __restrict__ gi0,
                float* __restrict__ gh) {
    const int wid = threadIdx.x >> 6, lane = threadIdx.x & 63;
    const int col = lane * 4;
    if (blockIdx.x < 1536) {
        const int k0 = (blockIdx.x * 4 + wid) * 2;
        const unsigned short* __restrict__ wr0 = whh_bf + (size_t)k0 * D;
        const unsigned short* __restrict__ wr1 = wr0 + D;
        float acc0[8] = {}, acc1[8] = {};
        u32x2 wa0 = *reinterpret_cast<const u32x2*>(wr0 + col);
        u32x2 wa1 = *reinterpret_cast<const u32x2*>(wr1 + col);
        for (int i = 0; i < 16; ++i) {
            const int idx  = i * 256 + col;
            const int nidx = ((i + 1) & 15) * 256 + col;
            f32x4 hv[8];
            #pragma unroll
            for (int j = 0; j < 8; ++j) hv[j] = ld4(h + j * D + idx);
            const u32x2 wb0 = *reinterpret_cast<const u32x2*>(wr0 + nidx);
            const u32x2 wb1 = *reinterpret_cast<const u32x2*>(wr1 + nidx);
            const float a0 = bf_lo(wa0.x), a1 = bf_hi(wa0.x);
            const float a2 = bf_lo(wa0.y), a3 = bf_hi(wa0.y);
            const float c0 = bf_lo(wa1.x), c1 = bf_hi(wa1.x);
            const float c2 = bf_lo(wa1.y), c3 = bf_hi(wa1.y);
            #pragma unroll
            for (int j = 0; j < 8; ++j) {
                acc0[j] += a0 * hv[j].x + a1 * hv[j].y + a2 * hv[j].z + a3 * hv[j].w;
                acc1[j] += c0 * hv[j].x + c1 * hv[j].y + c2 * hv[j].z + c3 * hv[j].w;
            }
            wa0 = wb0; wa1 = wb1;
        }
        #pragma unroll
        for (int j = 0; j < 8; ++j) {
            float v0 = acc0[j], v1 = acc1[j];
            #pragma unroll
            for (int off = 32; off; off >>= 1) {
                v0 += __shfl_xor(v0, off);
                v1 += __shfl_xor(v1, off);
            }
            if (lane == 0) {
                gh[(size_t)j * D3 + k0 + 0] = v0 + b_hh[k0 + 0];
                gh[(size_t)j * D3 + k0 + 1] = v1 + b_hh[k0 + 1];
            }
        }
    } else {
        const int k0 = ((blockIdx.x - 1536) * 4 + wid) * 4;
        const unsigned short* __restrict__ wr = wih_bf + (size_t)k0 * D;
        float acc[4] = {};
        u32x2 wa0 = *reinterpret_cast<const u32x2*>(wr + 0 * D + col);
        u32x2 wa1 = *reinterpret_cast<const u32x2*>(wr + 1 * D + col);
        u32x2 wa2 = *reinterpret_cast<const u32x2*>(wr + 2 * D + col);
        u32x2 wa3 = *reinterpret_cast<const u32x2*>(wr + 3 * D + col);
        for (int i = 0; i < 16; ++i) {
            const int idx  = i * 256 + col;
            const int nidx = ((i + 1) & 15) * 256 + col;
            const f32x4 av = ld4(aggmsg + idx);
            const u32x2 wb0 = *reinterpret_cast<const u32x2*>(wr + 0 * D + nidx);
            const u32x2 wb1 = *reinterpret_cast<const u32x2*>(wr + 1 * D + nidx);
            const u32x2 wb2 = *reinterpret_cast<const u32x2*>(wr + 2 * D + nidx);
            const u32x2 wb3 = *reinterpret_cast<const u32x2*>(wr + 3 * D + nidx);
            acc[0] += bf_lo(wa0.x) * av.x + bf_hi(wa0.x) * av.y
                    + bf_lo(wa0.y) * av.z + bf_hi(wa0.y) * av.w;
            acc[1] += bf_lo(wa1.x) * av.x + bf_hi(wa1.x) * av.y
                    + bf_lo(wa1.y) * av.z + bf_hi(wa1.y) * av.w;
            acc[2] += bf_lo(wa2.x) * av.x + bf_hi(wa2.x) * av.y
                    + bf_lo(wa2.y) * av.z + bf_hi(wa2.y) * av.w;
            acc[3] += bf_lo(wa3.x) * av.x + bf_hi(wa3.x) * av.y
                    + bf_lo(wa3.y) * av.z + bf_hi(wa3.y) * av.w;
            wa0 = wb0; wa1 = wb1; wa2 = wb2; wa3 = wb3;
        }
        #pragma unroll
        for (int r = 0; r < 4; ++r) {
            float v = acc[r];
            #pragma unroll
            for (int off = 32; off; off >>= 1) v += __shfl_xor(v, off);
            if (lane == 0) gi0[k0 + r] = v + b_ih[k0 + r];
        }
    }
}

// ---------------------------------------------------------------------------
// K6: GRU pointwise update; rows 0-3 (shared) use gi = b_ih (agg = 0).
// ---------------------------------------------------------------------------
__device__ __forceinline__ float sigmoidf_(float x) {
    return 1.0f / (1.0f + __expf(-x));
}

__global__ void k_gru(const float* __restrict__ gi0,
                      const float* __restrict__ gh,
                      const float* __restrict__ b_ih,
                      float* __restrict__ h,
                      float* __restrict__ svec) {
    const int d = blockIdx.x * 256 + threadIdx.x;
    const float bir = b_ih[d], biz = b_ih[D + d], bin = b_ih[2 * D + d];
    const float gir = gi0[d],  giz = gi0[D + d],  gin = gi0[2 * D + d];
    float ssum = 0.f;
    #pragma unroll
    for (int j = 0; j < 8; ++j) {
        const float ir = (j < 4) ? bir : gir;
        const float iz = (j < 4) ? biz : giz;
        const float in = (j < 4) ? bin : gin;
        const float hr = gh[(size_t)j * D3 + d];
        const float hz = gh[(size_t)j * D3 + D + d];
        const float hn = gh[(size_t)j * D3 + 2 * D + d];
        const float hv = h[j * D + d];
        const float r = sigmoidf_(ir + hr);
        const float z = sigmoidf_(iz + hz);
        const float n = tanhf(in + r * hn);
        const float hnew = (1.f - z) * n + z * hv;
        h[j * D + d] = hnew;
        if (j < 4) ssum += hnew;
    }
    svec[d] = ssum;
}

// ---------------------------------------------------------------------------
// K7: loss = 10 * sum_s mean_d (h0_s - pre_mean_s)^2.
// ---------------------------------------------------------------------------
__global__ void k_loss(const float* __restrict__ h,
                       const float* __restrict__ means,
                       float* __restrict__ out) {
    __shared__ float red[4];
    float acc = 0.f;
    for (int idx = threadIdx.x; idx < 4 * D; idx += 256) {
        const int s = idx >> 12;
        const int d = idx & (D - 1);
        const float diff = h[(4 + s) * D + d] - means[(4 + s) * D + d];
        acc += diff * diff;
    }
    #pragma unroll
    for (int off = 32; off; off >>= 1) acc += __shfl_xor(acc, off);
    const int wave = threadIdx.x >> 6, lane = threadIdx.x & 63;
    if (lane == 0) red[wave] = acc;
    __syncthreads();
    if (threadIdx.x == 0)
        out[0] = (red[0] + red[1] + red[2] + red[3]) * (10.0f / (float)D);
}

// ---------------------------------------------------------------------------
extern "C" void kernel_launch(void* const* d_in, const int* in_sizes, int n_in,
                              void* d_out, int out_size, void* d_ws, size_t ws_size,
                              hipStream_t stream) {
    const float* W    = (const float*)d_in[8];
    const float* w_ih = (const float*)d_in[9];
    const float* w_hh = (const float*)d_in[10];
    const float* b_ih = (const float*)d_in[11];
    const float* b_hh = (const float*)d_in[12];

    float* ws     = (float*)d_ws;
    float* mpart  = ws;                    // 8*64*D
    float* means  = mpart  + 8 * 64 * D;   // 8*D
    float* h      = means  + 8 * D;        // 8*D
    float* svec   = h      + 8 * D;        // D
    float* apart  = svec   + D;            // 256*D
    float* aggmsg = apart  + 256 * D;      // D
    float* gi0    = aggmsg + D;            // D3
    float* gh     = gi0    + D3;           // 8*D3
    float* wbase  = gh     + 8 * D3;
    unsigned short* wih_bf = (unsigned short*)wbase;   // D3*D bf16 = 96 MB
    unsigned short* whh_bf = wih_bf + (size_t)D3 * D;  // D3*D bf16 = 96 MB

    Ptrs8 in8;
    for (int i = 0; i < 8; ++i) in8.p[i] = (const float*)d_in[i];

    k_mean_partial<<<dim3(4, 64, 8), 256, 0, stream>>>(in8, mpart);
    k_mean_finalize<<<16, 256, 0, stream>>>(mpart, means, h, svec);

    for (int l = 0; l < L; ++l) {
        const float* Wl = W + (size_t)l * D * D;
        k_aggmsg_partial<<<dim3(4, 256), 256, 0, stream>>>(Wl, svec, apart);
        k_aggmsg_reduce<<<16, 256, 0, stream>>>(apart, aggmsg);
        if (l == 0)
            k_gates_f32<<<2304, 256, 0, stream>>>(w_ih, w_hh, h, aggmsg,
                                                  b_ih, b_hh, gi0, gh,
                                                  wih_bf, whh_bf);
        else
            k_gates_bf<<<2304, 256, 0, stream>>>(wih_bf, whh_bf, h, aggmsg,
                                                 b_ih, b_hh, gi0, gh);
        k_gru<<<16, 256, 0, stream>>>(gi0, gh, b_ih, h, svec);
    }

    k_loss<<<1, 256, 0, stream>>>(h, means, (float*)d_out);
}